// Round 3
// baseline (639.701 us; speedup 1.0000x reference)
//
#include <hip/hip_runtime.h>

#define N_PTS 16384
#define NH 16
#define NC 192
#define NK 43
#define ND 2
#define BN_EPS 1e-5f

typedef __attribute__((ext_vector_type(8))) short bf16x8;
typedef __attribute__((ext_vector_type(4))) float f32x4;

static __device__ __forceinline__ short f2bf(float f) {
    union { float f; unsigned u; } x; x.f = f;
    unsigned r = x.u + (0x7fffu + ((x.u >> 16) & 1u));   // RNE
    return (short)(r >> 16);
}
static __device__ __forceinline__ float bf2f(short s) {
    union { unsigned u; float f; } x; x.u = ((unsigned)(unsigned short)s) << 16;
    return x.f;
}

// ---------- copy feat -> X (f32 working buffer) ----------
__global__ void k_copy(const float* __restrict__ in, float* __restrict__ out, int n) {
    int i = blockIdx.x * blockDim.x + threadIdx.x;
    int stride = gridDim.x * blockDim.x;
    for (; i < n; i += stride) out[i] = in[i];
}

// ---------- pre-shuffle all weights into MFMA B-frag-ready bf16 layout ----------
// Frag element (nt, ks, lane, j) = W[k = ks*32 + (lane>>4)*8 + j][n = nt*16 + (lane&15)]
// Per-layer region: W1b[36864] | Wkb[12288] | W3b[36864]  (shorts), stride 86016.
__global__ __launch_bounds__(64) void k_wfrag(const float* __restrict__ W1,
                                              const float* __restrict__ Wk,
                                              const float* __restrict__ W3,
                                              short* __restrict__ Wb) {
    int b = blockIdx.x;
    int d = b / 168, r = b % 168;
    const float* src; short* dst; int kb, Ks, tile;
    if (r < 72)      { src = W1 + d * NC * NC; dst = Wb + d * 86016;         kb = 6; Ks = NC; tile = r; }
    else if (r < 96) { src = Wk + d * NK * NC; dst = Wb + d * 86016 + 36864; kb = 2; Ks = NK; tile = r - 72; }
    else             { src = W3 + d * NC * NC; dst = Wb + d * 86016 + 49152; kb = 6; Ks = NC; tile = r - 96; }
    int nt = tile / kb, ks = tile % kb;
    int lane = threadIdx.x, quad = lane >> 4, cl = lane & 15;
    short v[8];
#pragma unroll
    for (int j = 0; j < 8; ++j) {
        int k = ks * 32 + quad * 8 + j;
        int n = nt * 16 + cl;
        v[j] = (k < Ks) ? f2bf(src[k * NC + n]) : (short)0;
    }
    bf16x8* out = (bf16x8*)(dst + ((nt * kb + ks) * 64 + lane) * 8);
    bf16x8 vv;
#pragma unroll
    for (int j = 0; j < 8; ++j) vv[j] = v[j];
    *out = vv;
}

// ---------- stats finalize: combined scale a = g*rsqrt(var+eps), shift s = b - m*a ----------
__global__ __launch_bounds__(64) void k_stat2(const float* __restrict__ part, int nb,
                                              const float* __restrict__ g,
                                              const float* __restrict__ b,
                                              float* __restrict__ a_out,
                                              float* __restrict__ s_out) {
    int c = blockIdx.x * 64 + threadIdx.x;   // grid 3x64 = 192 channels
    float s = 0.f, sq = 0.f;
    for (int i = 0; i < nb; i += 4) {
        s  += part[(i + 0) * 384 + c]       + part[(i + 1) * 384 + c]
            + part[(i + 2) * 384 + c]       + part[(i + 3) * 384 + c];
        sq += part[(i + 0) * 384 + 192 + c] + part[(i + 1) * 384 + 192 + c]
            + part[(i + 2) * 384 + 192 + c] + part[(i + 3) * 384 + 192 + c];
    }
    float m = s * (1.f / N_PTS);
    float var = sq * (1.f / N_PTS) - m * m;
    float rs = rsqrtf(var + BN_EPS);
    float a = rs * g[c];
    a_out[c] = a;
    s_out[c] = b[c] - m * a;
}

// ---------- GEMM1: T(bf16) = X(f32) @ W1, + per-block BN partial sums ----------
// 256 threads = 4 waves; wave handles 16 rows; block = 64 rows; grid 256.
__global__ __launch_bounds__(256) void k_gemm1(const float* __restrict__ X,
                                               const short* __restrict__ Wb,
                                               short* __restrict__ T,
                                               float* __restrict__ part) {
    __shared__ float red[4][384];
    const int wave = threadIdx.x >> 6, lane = threadIdx.x & 63;
    const int quad = lane >> 4, cl = lane & 15;
    const int r0 = blockIdx.x * 64 + wave * 16;
    const int row = r0 + cl;

    f32x4 acc[12];
#pragma unroll
    for (int nt = 0; nt < 12; ++nt) acc[nt] = (f32x4){0.f, 0.f, 0.f, 0.f};

#pragma unroll
    for (int ks = 0; ks < 6; ++ks) {
        const float* ap = X + row * NC + ks * 32 + quad * 8;
        float4 a0 = *(const float4*)ap;
        float4 a1 = *(const float4*)(ap + 4);
        bf16x8 af;
        af[0] = f2bf(a0.x); af[1] = f2bf(a0.y); af[2] = f2bf(a0.z); af[3] = f2bf(a0.w);
        af[4] = f2bf(a1.x); af[5] = f2bf(a1.y); af[6] = f2bf(a1.z); af[7] = f2bf(a1.w);
#pragma unroll
        for (int nt = 0; nt < 12; ++nt) {
            bf16x8 bf = *(const bf16x8*)(Wb + ((nt * 6 + ks) * 64 + lane) * 8);
            acc[nt] = __builtin_amdgcn_mfma_f32_16x16x32_bf16(af, bf, acc[nt], 0, 0, 0);
        }
    }
    // epilogue: store T (bf16) + per-channel partial sums over this wave's 16 rows
#pragma unroll
    for (int nt = 0; nt < 12; ++nt) {
        int c = nt * 16 + cl;
        float s = 0.f, sq = 0.f;
#pragma unroll
        for (int r = 0; r < 4; ++r) {
            float v = acc[nt][r];
            T[(r0 + quad * 4 + r) * NC + c] = f2bf(v);
            s += v; sq = fmaf(v, v, sq);
        }
        s += __shfl_xor(s, 16); s += __shfl_xor(s, 32);
        sq += __shfl_xor(sq, 16); sq += __shfl_xor(sq, 32);
        if (quad == 0) { red[wave][c] = s; red[wave][192 + c] = sq; }
    }
    __syncthreads();
    for (int t = threadIdx.x; t < 384; t += 256)
        part[blockIdx.x * 384 + t] = red[0][t] + red[1][t] + red[2][t] + red[3][t];
}

// ---------- GEMM3: T2(bf16) = relu(bn2(U)) @ W3, + partial sums ----------
__global__ __launch_bounds__(256) void k_gemm3(const short* __restrict__ U,
                                               const float* __restrict__ a2,
                                               const float* __restrict__ s2,
                                               const short* __restrict__ Wb,
                                               short* __restrict__ T2,
                                               float* __restrict__ part) {
    __shared__ float red[4][384];
    const int wave = threadIdx.x >> 6, lane = threadIdx.x & 63;
    const int quad = lane >> 4, cl = lane & 15;
    const int r0 = blockIdx.x * 64 + wave * 16;
    const int row = r0 + cl;

    f32x4 acc[12];
#pragma unroll
    for (int nt = 0; nt < 12; ++nt) acc[nt] = (f32x4){0.f, 0.f, 0.f, 0.f};

#pragma unroll
    for (int ks = 0; ks < 6; ++ks) {
        const int k0 = ks * 32 + quad * 8;
        bf16x8 u8 = *(const bf16x8*)(U + row * NC + k0);
        float4 aa0 = *(const float4*)(a2 + k0), aa1 = *(const float4*)(a2 + k0 + 4);
        float4 ss0 = *(const float4*)(s2 + k0), ss1 = *(const float4*)(s2 + k0 + 4);
        float av[8] = {aa0.x, aa0.y, aa0.z, aa0.w, aa1.x, aa1.y, aa1.z, aa1.w};
        float sv[8] = {ss0.x, ss0.y, ss0.z, ss0.w, ss1.x, ss1.y, ss1.z, ss1.w};
        bf16x8 af;
#pragma unroll
        for (int j = 0; j < 8; ++j)
            af[j] = f2bf(fmaxf(fmaf(av[j], bf2f(u8[j]), sv[j]), 0.f));
#pragma unroll
        for (int nt = 0; nt < 12; ++nt) {
            bf16x8 bf = *(const bf16x8*)(Wb + ((nt * 6 + ks) * 64 + lane) * 8);
            acc[nt] = __builtin_amdgcn_mfma_f32_16x16x32_bf16(af, bf, acc[nt], 0, 0, 0);
        }
    }
#pragma unroll
    for (int nt = 0; nt < 12; ++nt) {
        int c = nt * 16 + cl;
        float s = 0.f, sq = 0.f;
#pragma unroll
        for (int r = 0; r < 4; ++r) {
            float v = acc[nt][r];
            T2[(r0 + quad * 4 + r) * NC + c] = f2bf(v);
            s += v; sq = fmaf(v, v, sq);
        }
        s += __shfl_xor(s, 16); s += __shfl_xor(s, 32);
        sq += __shfl_xor(sq, 16); sq += __shfl_xor(sq, 32);
        if (quad == 0) { red[wave][c] = s; red[wave][192 + c] = sq; }
    }
    __syncthreads();
    for (int t = threadIdx.x; t < 384; t += 256)
        part[blockIdx.x * 384 + t] = red[0][t] + red[1][t] + red[2][t] + red[3][t];
}

// ---------- fused KPConv: U = sum_h (infl @ Wk)[h,c] * relu(bn1(T[ref]))[h,c] ----------
// 256 threads = 4 waves; block = 16 points; wave handles 4 points (each = one MFMA M-tile).
// Influence A-fragments computed IN REGISTERS (no LDS round-trip, no A materialization).
__global__ __launch_bounds__(256) void k_kpconv(const float* __restrict__ coord,
                                                const int* __restrict__ ref_idx,
                                                const float* __restrict__ kp,
                                                const short* __restrict__ Wkb,
                                                const short* __restrict__ T,
                                                const float* __restrict__ a1,
                                                const float* __restrict__ s1,
                                                short* __restrict__ U,
                                                float* __restrict__ part) {
    __shared__ float kp_s[64][3];
    __shared__ int idx_s[16][16];
    __shared__ float nb_s[16][16][3];
    __shared__ float a1_s[192], s1_s[192];
    __shared__ float red[4][384];

    const int tid = threadIdx.x;
    const int wave = tid >> 6, lane = tid & 63;
    const int quad = lane >> 4, cl = lane & 15;

    if (tid < 64) {
        bool ok = tid < NK;
        kp_s[tid][0] = ok ? kp[tid * 3 + 0] : 0.f;
        kp_s[tid][1] = ok ? kp[tid * 3 + 1] : 0.f;
        kp_s[tid][2] = ok ? kp[tid * 3 + 2] : 0.f;
    }
    if (tid < 192) { a1_s[tid] = a1[tid]; s1_s[tid] = s1[tid]; }
    {
        int p = tid >> 4, h = tid & 15;
        int n = blockIdx.x * 16 + p;
        int id = ref_idx[n * NH + h];
        idx_s[p][h] = id;
        nb_s[p][h][0] = coord[id * 3 + 0] - coord[n * 3 + 0];
        nb_s[p][h][1] = coord[id * 3 + 1] - coord[n * 3 + 1];
        nb_s[p][h][2] = coord[id * 3 + 2] - coord[n * 3 + 2];
    }
    __syncthreads();

    float su[12], squ[12];
#pragma unroll
    for (int nt = 0; nt < 12; ++nt) { su[nt] = 0.f; squ[nt] = 0.f; }

    for (int pp = 0; pp < 4; ++pp) {
        const int p = wave * 4 + pp;
        const int n = blockIdx.x * 16 + p;
        // --- influence A-fragments, in registers: A[m = cl (h)][k = ks*32+quad*8+j]
        const float nx = nb_s[p][cl][0], ny = nb_s[p][cl][1], nz = nb_s[p][cl][2];
        bf16x8 af[2];
#pragma unroll
        for (int ks = 0; ks < 2; ++ks) {
#pragma unroll
            for (int j = 0; j < 8; ++j) {
                int k = ks * 32 + quad * 8 + j;
                float dx = nx - kp_s[k][0];
                float dy = ny - kp_s[k][1];
                float dz = nz - kp_s[k][2];
                float d = sqrtf(fmaf(dx, dx, fmaf(dy, dy, dz * dz)));
                float w = fmaxf(1.f - d, 0.f);         // SIGMA = 1
                if (k >= NK) w = 0.f;                  // mask the K padding
                af[ks][j] = f2bf(w);
            }
        }
        // --- A = infl @ Wk via MFMA (12 n-tiles x 2 k-steps)
        f32x4 acc[12];
#pragma unroll
        for (int nt = 0; nt < 12; ++nt) {
            bf16x8 b0 = *(const bf16x8*)(Wkb + ((nt * 2 + 0) * 64 + lane) * 8);
            bf16x8 b1 = *(const bf16x8*)(Wkb + ((nt * 2 + 1) * 64 + lane) * 8);
            f32x4 z = (f32x4){0.f, 0.f, 0.f, 0.f};
            z = __builtin_amdgcn_mfma_f32_16x16x32_bf16(af[0], b0, z, 0, 0, 0);
            acc[nt] = __builtin_amdgcn_mfma_f32_16x16x32_bf16(af[1], b1, z, 0, 0, 0);
        }
        // --- aggregate: U[n,c] = sum_h acc[h,c] * relu(bn1(T[idx[h],c]))
        int rowb[4];
#pragma unroll
        for (int r = 0; r < 4; ++r) rowb[r] = idx_s[p][quad * 4 + r] * NC;
#pragma unroll
        for (int nt = 0; nt < 12; ++nt) {
            int c = nt * 16 + cl;
            float a1c = a1_s[c], s1c = s1_s[c];
            float u = 0.f;
#pragma unroll
            for (int r = 0; r < 4; ++r) {
                float t = bf2f(T[rowb[r] + c]);
                float x = fmaxf(fmaf(a1c, t, s1c), 0.f);
                u = fmaf(acc[nt][r], x, u);
            }
            u += __shfl_xor(u, 16); u += __shfl_xor(u, 32);
            if (quad == 0) U[n * NC + c] = f2bf(u);
            su[nt] += u; squ[nt] = fmaf(u, u, squ[nt]);
        }
    }
    // --- per-block BN2 partial sums
    if (quad == 0) {
#pragma unroll
        for (int nt = 0; nt < 12; ++nt) {
            red[wave][nt * 16 + cl] = su[nt];
            red[wave][192 + nt * 16 + cl] = squ[nt];
        }
    }
    __syncthreads();
    for (int t = tid; t < 384; t += 256)
        part[blockIdx.x * 384 + t] = red[0][t] + red[1][t] + red[2][t] + red[3][t];
}

// ---------- skip: X = relu(X + bn3(T2)); last layer writes d_out instead ----------
__global__ __launch_bounds__(192) void k_bnskip(const short* __restrict__ T2,
                                                const float* __restrict__ a3,
                                                const float* __restrict__ s3,
                                                float* __restrict__ X,
                                                float* __restrict__ out) {
    const int c = threadIdx.x;
    const float a = a3[c], s = s3[c];
    const int base = blockIdx.x * 16;
#pragma unroll
    for (int r = 0; r < 16; ++r) {
        int i = (base + r) * NC + c;
        float v = fmaf(a, bf2f(T2[i]), s);
        float x = fmaxf(X[i] + v, 0.f);
        if (out) out[i] = x; else X[i] = x;
    }
}

extern "C" void kernel_launch(void* const* d_in, const int* in_sizes, int n_in,
                              void* d_out, int out_size, void* d_ws, size_t ws_size,
                              hipStream_t stream) {
    const float* coord = (const float*)d_in[0];
    const float* feat  = (const float*)d_in[1];
    const int*   ridx  = (const int*)d_in[2];
    const float* kp    = (const float*)d_in[3];
    const float* W1    = (const float*)d_in[4];
    const float* Wk    = (const float*)d_in[5];
    const float* W3    = (const float*)d_in[6];
    const float* g1    = (const float*)d_in[7];
    const float* b1    = (const float*)d_in[8];
    const float* g2    = (const float*)d_in[9];
    const float* b2    = (const float*)d_in[10];
    const float* g3    = (const float*)d_in[11];
    const float* b3    = (const float*)d_in[12];
    float* out = (float*)d_out;

    // ws: X f32 | T bf16 | U bf16 | T2 bf16 | Wb bf16 | part f32 | stats f32  ~= 33.4 MB
    float* X   = (float*)d_ws;
    short* T   = (short*)(X + N_PTS * NC);
    short* Ub  = T + N_PTS * NC;
    short* T2  = Ub + N_PTS * NC;
    short* Wb  = T2 + N_PTS * NC;
    float* part = (float*)(Wb + 2 * 86016);
    float* stats = part + 1024 * 384;   // 6 sites x (a[192], s[192])

    k_wfrag<<<336, 64, 0, stream>>>(W1, Wk, W3, Wb);
    k_copy<<<2048, 256, 0, stream>>>(feat, X, N_PTS * NC);

    for (int d = 0; d < ND; ++d) {
        const short* W1b = Wb + d * 86016;
        const short* Wkb = W1b + 36864;
        const short* W3b = W1b + 49152;
        float* st1 = stats + (d * 3 + 0) * 384;
        float* st2 = stats + (d * 3 + 1) * 384;
        float* st3 = stats + (d * 3 + 2) * 384;

        k_gemm1<<<256, 256, 0, stream>>>(X, W1b, T, part);
        k_stat2<<<3, 64, 0, stream>>>(part, 256, g1 + d * NC, b1 + d * NC, st1, st1 + 192);
        k_kpconv<<<1024, 256, 0, stream>>>(coord, ridx, kp, Wkb, T, st1, st1 + 192, Ub, part);
        k_stat2<<<3, 64, 0, stream>>>(part, 1024, g2 + d * NC, b2 + d * NC, st2, st2 + 192);
        k_gemm3<<<256, 256, 0, stream>>>(Ub, st2, st2 + 192, W3b, T2, part);
        k_stat2<<<3, 64, 0, stream>>>(part, 256, g3 + d * NC, b3 + d * NC, st3, st3 + 192);
        k_bnskip<<<1024, 192, 0, stream>>>(T2, st3, st3 + 192, X,
                                           (d == ND - 1) ? out : (float*)nullptr);
    }
}

// Round 4
// 401.836 us; speedup vs baseline: 1.5919x; 1.5919x over previous
//
#include <hip/hip_runtime.h>

#define N_PTS 16384
#define NH 16
#define NC 192
#define NK 43
#define ND 2
#define BN_EPS 1e-5f

typedef __attribute__((ext_vector_type(8))) short bf16x8;
typedef __attribute__((ext_vector_type(4))) float f32x4;

static __device__ __forceinline__ short f2bf(float f) {
    union { float f; unsigned u; } x; x.f = f;
    unsigned r = x.u + (0x7fffu + ((x.u >> 16) & 1u));   // RNE
    return (short)(r >> 16);
}
static __device__ __forceinline__ float bf2f(short s) {
    union { unsigned u; float f; } x; x.u = ((unsigned)(unsigned short)s) << 16;
    return x.f;
}

// ---------- copy feat -> X (f32 working buffer) ----------
__global__ void k_copy(const float* __restrict__ in, float* __restrict__ out, int n) {
    int i = blockIdx.x * blockDim.x + threadIdx.x;
    int stride = gridDim.x * blockDim.x;
    for (; i < n; i += stride) out[i] = in[i];
}

// ---------- pre-shuffle all weights into MFMA B-frag-ready bf16 layout ----------
// Frag element (nt, ks, lane, j) = W[k = ks*32 + (lane>>4)*8 + j][n = nt*16 + (lane&15)]
// Per-layer region: W1b[36864] | Wkb[12288] | W3b[36864]  (shorts), stride 86016.
__global__ __launch_bounds__(64) void k_wfrag(const float* __restrict__ W1,
                                              const float* __restrict__ Wk,
                                              const float* __restrict__ W3,
                                              short* __restrict__ Wb) {
    int b = blockIdx.x;
    int d = b / 168, r = b % 168;
    const float* src; short* dst; int kb, Ks, tile;
    if (r < 72)      { src = W1 + d * NC * NC; dst = Wb + d * 86016;         kb = 6; Ks = NC; tile = r; }
    else if (r < 96) { src = Wk + d * NK * NC; dst = Wb + d * 86016 + 36864; kb = 2; Ks = NK; tile = r - 72; }
    else             { src = W3 + d * NC * NC; dst = Wb + d * 86016 + 49152; kb = 6; Ks = NC; tile = r - 96; }
    int nt = tile / kb, ks = tile % kb;
    int lane = threadIdx.x, quad = lane >> 4, cl = lane & 15;
    short v[8];
#pragma unroll
    for (int j = 0; j < 8; ++j) {
        int k = ks * 32 + quad * 8 + j;
        int n = nt * 16 + cl;
        v[j] = (k < Ks) ? f2bf(src[k * NC + n]) : (short)0;
    }
    bf16x8* out = (bf16x8*)(dst + ((nt * kb + ks) * 64 + lane) * 8);
    bf16x8 vv;
#pragma unroll
    for (int j = 0; j < 8; ++j) vv[j] = v[j];
    *out = vv;
}

// ---------- stats finalize: a = g*rsqrt(var+eps), s = b - m*a ----------
// grid = 192 blocks (one channel each), 128 threads: wave0 -> sum, wave1 -> sumsq.
__global__ __launch_bounds__(128) void k_stat2(const float* __restrict__ part, int nb,
                                               const float* __restrict__ g,
                                               const float* __restrict__ b,
                                               float* __restrict__ a_out,
                                               float* __restrict__ s_out) {
    __shared__ float red2[2];
    const int c = blockIdx.x;
    const int tid = threadIdx.x;
    const int lane = tid & 63;
    const int half = tid >> 6;                 // 0: sum, 1: sumsq
    const float* src = part + (half ? 192 + c : c);
    float s = 0.f;
    for (int i = lane; i < nb; i += 64) s += src[i * 384];
    s += __shfl_xor(s, 1);  s += __shfl_xor(s, 2);  s += __shfl_xor(s, 4);
    s += __shfl_xor(s, 8);  s += __shfl_xor(s, 16); s += __shfl_xor(s, 32);
    if (lane == 0) red2[half] = s;
    __syncthreads();
    if (tid == 0) {
        float m = red2[0] * (1.f / N_PTS);
        float var = red2[1] * (1.f / N_PTS) - m * m;
        float rs = rsqrtf(var + BN_EPS);
        float a = rs * g[c];
        a_out[c] = a;
        s_out[c] = b[c] - m * a;
    }
}

// ---------- GEMM1: T(bf16) = X(f32) @ W1, + per-block BN partial sums ----------
// 256 threads = 4 waves; wave handles 16 rows; block = 64 rows; grid 256.
__global__ __launch_bounds__(256) void k_gemm1(const float* __restrict__ X,
                                               const short* __restrict__ Wb,
                                               short* __restrict__ T,
                                               float* __restrict__ part) {
    __shared__ float red[4][384];
    const int wave = threadIdx.x >> 6, lane = threadIdx.x & 63;
    const int quad = lane >> 4, cl = lane & 15;
    const int r0 = blockIdx.x * 64 + wave * 16;
    const int row = r0 + cl;

    f32x4 acc[12];
#pragma unroll
    for (int nt = 0; nt < 12; ++nt) acc[nt] = (f32x4){0.f, 0.f, 0.f, 0.f};

#pragma unroll
    for (int ks = 0; ks < 6; ++ks) {
        const float* ap = X + row * NC + ks * 32 + quad * 8;
        float4 a0 = *(const float4*)ap;
        float4 a1 = *(const float4*)(ap + 4);
        bf16x8 af;
        af[0] = f2bf(a0.x); af[1] = f2bf(a0.y); af[2] = f2bf(a0.z); af[3] = f2bf(a0.w);
        af[4] = f2bf(a1.x); af[5] = f2bf(a1.y); af[6] = f2bf(a1.z); af[7] = f2bf(a1.w);
#pragma unroll
        for (int nt = 0; nt < 12; ++nt) {
            bf16x8 bf = *(const bf16x8*)(Wb + ((nt * 6 + ks) * 64 + lane) * 8);
            acc[nt] = __builtin_amdgcn_mfma_f32_16x16x32_bf16(af, bf, acc[nt], 0, 0, 0);
        }
    }
    // epilogue: store T (bf16) + per-channel partial sums over this wave's 16 rows
#pragma unroll
    for (int nt = 0; nt < 12; ++nt) {
        int c = nt * 16 + cl;
        float s = 0.f, sq = 0.f;
#pragma unroll
        for (int r = 0; r < 4; ++r) {
            float v = acc[nt][r];
            T[(r0 + quad * 4 + r) * NC + c] = f2bf(v);
            s += v; sq = fmaf(v, v, sq);
        }
        s += __shfl_xor(s, 16); s += __shfl_xor(s, 32);
        sq += __shfl_xor(sq, 16); sq += __shfl_xor(sq, 32);
        if (quad == 0) { red[wave][c] = s; red[wave][192 + c] = sq; }
    }
    __syncthreads();
    for (int t = threadIdx.x; t < 384; t += 256)
        part[blockIdx.x * 384 + t] = red[0][t] + red[1][t] + red[2][t] + red[3][t];
}

// ---------- GEMM3: T2(bf16) = relu(bn2(U)) @ W3, + partial sums ----------
__global__ __launch_bounds__(256) void k_gemm3(const short* __restrict__ U,
                                               const float* __restrict__ a2,
                                               const float* __restrict__ s2,
                                               const short* __restrict__ Wb,
                                               short* __restrict__ T2,
                                               float* __restrict__ part) {
    __shared__ float red[4][384];
    const int wave = threadIdx.x >> 6, lane = threadIdx.x & 63;
    const int quad = lane >> 4, cl = lane & 15;
    const int r0 = blockIdx.x * 64 + wave * 16;
    const int row = r0 + cl;

    f32x4 acc[12];
#pragma unroll
    for (int nt = 0; nt < 12; ++nt) acc[nt] = (f32x4){0.f, 0.f, 0.f, 0.f};

#pragma unroll
    for (int ks = 0; ks < 6; ++ks) {
        const int k0 = ks * 32 + quad * 8;
        bf16x8 u8 = *(const bf16x8*)(U + row * NC + k0);
        float4 aa0 = *(const float4*)(a2 + k0), aa1 = *(const float4*)(a2 + k0 + 4);
        float4 ss0 = *(const float4*)(s2 + k0), ss1 = *(const float4*)(s2 + k0 + 4);
        float av[8] = {aa0.x, aa0.y, aa0.z, aa0.w, aa1.x, aa1.y, aa1.z, aa1.w};
        float sv[8] = {ss0.x, ss0.y, ss0.z, ss0.w, ss1.x, ss1.y, ss1.z, ss1.w};
        bf16x8 af;
#pragma unroll
        for (int j = 0; j < 8; ++j)
            af[j] = f2bf(fmaxf(fmaf(av[j], bf2f(u8[j]), sv[j]), 0.f));
#pragma unroll
        for (int nt = 0; nt < 12; ++nt) {
            bf16x8 bf = *(const bf16x8*)(Wb + ((nt * 6 + ks) * 64 + lane) * 8);
            acc[nt] = __builtin_amdgcn_mfma_f32_16x16x32_bf16(af, bf, acc[nt], 0, 0, 0);
        }
    }
#pragma unroll
    for (int nt = 0; nt < 12; ++nt) {
        int c = nt * 16 + cl;
        float s = 0.f, sq = 0.f;
#pragma unroll
        for (int r = 0; r < 4; ++r) {
            float v = acc[nt][r];
            T2[(r0 + quad * 4 + r) * NC + c] = f2bf(v);
            s += v; sq = fmaf(v, v, sq);
        }
        s += __shfl_xor(s, 16); s += __shfl_xor(s, 32);
        sq += __shfl_xor(sq, 16); sq += __shfl_xor(sq, 32);
        if (quad == 0) { red[wave][c] = s; red[wave][192 + c] = sq; }
    }
    __syncthreads();
    for (int t = threadIdx.x; t < 384; t += 256)
        part[blockIdx.x * 384 + t] = red[0][t] + red[1][t] + red[2][t] + red[3][t];
}

// ---------- fused KPConv: U = sum_h (infl @ Wk)[h,c] * relu(bn1(T[ref]))[h,c] ----------
// 256 threads = 4 waves; block = 16 points; wave handles 4 points (each = one MFMA M-tile).
// Influence A-fragments computed IN REGISTERS (no LDS round-trip, no A materialization).
__global__ __launch_bounds__(256) void k_kpconv(const float* __restrict__ coord,
                                                const int* __restrict__ ref_idx,
                                                const float* __restrict__ kp,
                                                const short* __restrict__ Wkb,
                                                const short* __restrict__ T,
                                                const float* __restrict__ a1,
                                                const float* __restrict__ s1,
                                                short* __restrict__ U,
                                                float* __restrict__ part) {
    __shared__ float kp_s[64][3];
    __shared__ int idx_s[16][16];
    __shared__ float nb_s[16][16][3];
    __shared__ float a1_s[192], s1_s[192];
    __shared__ float red[4][384];

    const int tid = threadIdx.x;
    const int wave = tid >> 6, lane = tid & 63;
    const int quad = lane >> 4, cl = lane & 15;

    if (tid < 64) {
        bool ok = tid < NK;
        kp_s[tid][0] = ok ? kp[tid * 3 + 0] : 0.f;
        kp_s[tid][1] = ok ? kp[tid * 3 + 1] : 0.f;
        kp_s[tid][2] = ok ? kp[tid * 3 + 2] : 0.f;
    }
    if (tid < 192) { a1_s[tid] = a1[tid]; s1_s[tid] = s1[tid]; }
    {
        int p = tid >> 4, h = tid & 15;
        int n = blockIdx.x * 16 + p;
        int id = ref_idx[n * NH + h];
        idx_s[p][h] = id;
        nb_s[p][h][0] = coord[id * 3 + 0] - coord[n * 3 + 0];
        nb_s[p][h][1] = coord[id * 3 + 1] - coord[n * 3 + 1];
        nb_s[p][h][2] = coord[id * 3 + 2] - coord[n * 3 + 2];
    }
    __syncthreads();

    float su[12], squ[12];
#pragma unroll
    for (int nt = 0; nt < 12; ++nt) { su[nt] = 0.f; squ[nt] = 0.f; }

    for (int pp = 0; pp < 4; ++pp) {
        const int p = wave * 4 + pp;
        const int n = blockIdx.x * 16 + p;
        // --- influence A-fragments, in registers: A[m = cl (h)][k = ks*32+quad*8+j]
        const float nx = nb_s[p][cl][0], ny = nb_s[p][cl][1], nz = nb_s[p][cl][2];
        bf16x8 af[2];
#pragma unroll
        for (int ks = 0; ks < 2; ++ks) {
#pragma unroll
            for (int j = 0; j < 8; ++j) {
                int k = ks * 32 + quad * 8 + j;
                float dx = nx - kp_s[k][0];
                float dy = ny - kp_s[k][1];
                float dz = nz - kp_s[k][2];
                float d = sqrtf(fmaf(dx, dx, fmaf(dy, dy, dz * dz)));
                float w = fmaxf(1.f - d, 0.f);         // SIGMA = 1
                if (k >= NK) w = 0.f;                  // mask the K padding
                af[ks][j] = f2bf(w);
            }
        }
        // --- A = infl @ Wk via MFMA (12 n-tiles x 2 k-steps)
        f32x4 acc[12];
#pragma unroll
        for (int nt = 0; nt < 12; ++nt) {
            bf16x8 b0 = *(const bf16x8*)(Wkb + ((nt * 2 + 0) * 64 + lane) * 8);
            bf16x8 b1 = *(const bf16x8*)(Wkb + ((nt * 2 + 1) * 64 + lane) * 8);
            f32x4 z = (f32x4){0.f, 0.f, 0.f, 0.f};
            z = __builtin_amdgcn_mfma_f32_16x16x32_bf16(af[0], b0, z, 0, 0, 0);
            acc[nt] = __builtin_amdgcn_mfma_f32_16x16x32_bf16(af[1], b1, z, 0, 0, 0);
        }
        // --- aggregate: U[n,c] = sum_h acc[h,c] * relu(bn1(T[idx[h],c]))
        int rowb[4];
#pragma unroll
        for (int r = 0; r < 4; ++r) rowb[r] = idx_s[p][quad * 4 + r] * NC;
#pragma unroll
        for (int nt = 0; nt < 12; ++nt) {
            int c = nt * 16 + cl;
            float a1c = a1_s[c], s1c = s1_s[c];
            float u = 0.f;
#pragma unroll
            for (int r = 0; r < 4; ++r) {
                float t = bf2f(T[rowb[r] + c]);
                float x = fmaxf(fmaf(a1c, t, s1c), 0.f);
                u = fmaf(acc[nt][r], x, u);
            }
            u += __shfl_xor(u, 16); u += __shfl_xor(u, 32);
            if (quad == 0) U[n * NC + c] = f2bf(u);
            su[nt] += u; squ[nt] = fmaf(u, u, squ[nt]);
        }
    }
    // --- per-block BN2 partial sums
    if (quad == 0) {
#pragma unroll
        for (int nt = 0; nt < 12; ++nt) {
            red[wave][nt * 16 + cl] = su[nt];
            red[wave][192 + nt * 16 + cl] = squ[nt];
        }
    }
    __syncthreads();
    for (int t = tid; t < 384; t += 256)
        part[blockIdx.x * 384 + t] = red[0][t] + red[1][t] + red[2][t] + red[3][t];
}

// ---------- skip: X = relu(X + bn3(T2)); last layer writes d_out instead ----------
__global__ __launch_bounds__(192) void k_bnskip(const short* __restrict__ T2,
                                                const float* __restrict__ a3,
                                                const float* __restrict__ s3,
                                                float* __restrict__ X,
                                                float* __restrict__ out) {
    const int c = threadIdx.x;
    const float a = a3[c], s = s3[c];
    const int base = blockIdx.x * 16;
#pragma unroll
    for (int r = 0; r < 16; ++r) {
        int i = (base + r) * NC + c;
        float v = fmaf(a, bf2f(T2[i]), s);
        float x = fmaxf(X[i] + v, 0.f);
        if (out) out[i] = x; else X[i] = x;
    }
}

extern "C" void kernel_launch(void* const* d_in, const int* in_sizes, int n_in,
                              void* d_out, int out_size, void* d_ws, size_t ws_size,
                              hipStream_t stream) {
    const float* coord = (const float*)d_in[0];
    const float* feat  = (const float*)d_in[1];
    const int*   ridx  = (const int*)d_in[2];
    const float* kp    = (const float*)d_in[3];
    const float* W1    = (const float*)d_in[4];
    const float* Wk    = (const float*)d_in[5];
    const float* W3    = (const float*)d_in[6];
    const float* g1    = (const float*)d_in[7];
    const float* b1    = (const float*)d_in[8];
    const float* g2    = (const float*)d_in[9];
    const float* b2    = (const float*)d_in[10];
    const float* g3    = (const float*)d_in[11];
    const float* b3    = (const float*)d_in[12];
    float* out = (float*)d_out;

    // ws: X f32 | T bf16 | U bf16 | T2 bf16 | Wb bf16 | part f32 | stats f32  ~= 33.4 MB
    float* X   = (float*)d_ws;
    short* T   = (short*)(X + N_PTS * NC);
    short* Ub  = T + N_PTS * NC;
    short* T2  = Ub + N_PTS * NC;
    short* Wb  = T2 + N_PTS * NC;
    float* part = (float*)(Wb + 2 * 86016);
    float* stats = part + 1024 * 384;   // 6 sites x (a[192], s[192])

    k_wfrag<<<336, 64, 0, stream>>>(W1, Wk, W3, Wb);
    k_copy<<<2048, 256, 0, stream>>>(feat, X, N_PTS * NC);

    for (int d = 0; d < ND; ++d) {
        const short* W1b = Wb + d * 86016;
        const short* Wkb = W1b + 36864;
        const short* W3b = W1b + 49152;
        float* st1 = stats + (d * 3 + 0) * 384;
        float* st2 = stats + (d * 3 + 1) * 384;
        float* st3 = stats + (d * 3 + 2) * 384;

        k_gemm1<<<256, 256, 0, stream>>>(X, W1b, T, part);
        k_stat2<<<192, 128, 0, stream>>>(part, 256, g1 + d * NC, b1 + d * NC, st1, st1 + 192);
        k_kpconv<<<1024, 256, 0, stream>>>(coord, ridx, kp, Wkb, T, st1, st1 + 192, Ub, part);
        k_stat2<<<192, 128, 0, stream>>>(part, 1024, g2 + d * NC, b2 + d * NC, st2, st2 + 192);
        k_gemm3<<<256, 256, 0, stream>>>(Ub, st2, st2 + 192, W3b, T2, part);
        k_stat2<<<192, 128, 0, stream>>>(part, 256, g3 + d * NC, b3 + d * NC, st3, st3 + 192);
        k_bnskip<<<1024, 192, 0, stream>>>(T2, st3, st3 + 192, X,
                                           (d == ND - 1) ? out : (float*)nullptr);
    }
}

// Round 5
// 318.231 us; speedup vs baseline: 2.0102x; 1.2627x over previous
//
#include <hip/hip_runtime.h>

#define N_PTS 16384
#define NH 16
#define NC 192
#define NK 43
#define ND 2
#define BN_EPS 1e-5f

typedef __attribute__((ext_vector_type(8))) short bf16x8;
typedef __attribute__((ext_vector_type(4))) float f32x4;

static __device__ __forceinline__ short f2bf(float f) {
    union { float f; unsigned u; } x; x.f = f;
    unsigned r = x.u + (0x7fffu + ((x.u >> 16) & 1u));   // RNE
    return (short)(r >> 16);
}
static __device__ __forceinline__ float bf2f(short s) {
    union { unsigned u; float f; } x; x.u = ((unsigned)(unsigned short)s) << 16;
    return x.f;
}

// ---------- copy feat -> X (f32 working buffer) ----------
__global__ void k_copy(const float* __restrict__ in, float* __restrict__ out, int n) {
    int i = blockIdx.x * blockDim.x + threadIdx.x;
    int stride = gridDim.x * blockDim.x;
    for (; i < n; i += stride) out[i] = in[i];
}

// ---------- pre-shuffle all weights into MFMA B-frag-ready bf16 layout ----------
// Frag element (nt, ks, lane, j) = W[k = ks*32 + (lane>>4)*8 + j][n = nt*16 + (lane&15)]
// Per-layer region: W1b[36864] | Wkb[12288] | W3b[36864]  (shorts), stride 86016.
__global__ __launch_bounds__(64) void k_wfrag(const float* __restrict__ W1,
                                              const float* __restrict__ Wk,
                                              const float* __restrict__ W3,
                                              short* __restrict__ Wb) {
    int b = blockIdx.x;
    int d = b / 168, r = b % 168;
    const float* src; short* dst; int kb, Ks, tile;
    if (r < 72)      { src = W1 + d * NC * NC; dst = Wb + d * 86016;         kb = 6; Ks = NC; tile = r; }
    else if (r < 96) { src = Wk + d * NK * NC; dst = Wb + d * 86016 + 36864; kb = 2; Ks = NK; tile = r - 72; }
    else             { src = W3 + d * NC * NC; dst = Wb + d * 86016 + 49152; kb = 6; Ks = NC; tile = r - 96; }
    int nt = tile / kb, ks = tile % kb;
    int lane = threadIdx.x, quad = lane >> 4, cl = lane & 15;
    short v[8];
#pragma unroll
    for (int j = 0; j < 8; ++j) {
        int k = ks * 32 + quad * 8 + j;
        int n = nt * 16 + cl;
        v[j] = (k < Ks) ? f2bf(src[k * NC + n]) : (short)0;
    }
    bf16x8* out = (bf16x8*)(dst + ((nt * kb + ks) * 64 + lane) * 8);
    bf16x8 vv;
#pragma unroll
    for (int j = 0; j < 8; ++j) vv[j] = v[j];
    *out = vv;
}

// ---------- stats finalize: a = g*rsqrt(var+eps), s = b - m*a ----------
// grid = 192 blocks (one channel each), 128 threads: wave0 -> sum, wave1 -> sumsq.
__global__ __launch_bounds__(128) void k_stat2(const float* __restrict__ part, int nb,
                                               const float* __restrict__ g,
                                               const float* __restrict__ b,
                                               float* __restrict__ a_out,
                                               float* __restrict__ s_out) {
    __shared__ float red2[2];
    const int c = blockIdx.x;
    const int tid = threadIdx.x;
    const int lane = tid & 63;
    const int half = tid >> 6;                 // 0: sum, 1: sumsq
    const float* src = part + (half ? 192 + c : c);
    float s = 0.f;
    for (int i = lane; i < nb; i += 64) s += src[i * 384];
    s += __shfl_xor(s, 1);  s += __shfl_xor(s, 2);  s += __shfl_xor(s, 4);
    s += __shfl_xor(s, 8);  s += __shfl_xor(s, 16); s += __shfl_xor(s, 32);
    if (lane == 0) red2[half] = s;
    __syncthreads();
    if (tid == 0) {
        float m = red2[0] * (1.f / N_PTS);
        float var = red2[1] * (1.f / N_PTS) - m * m;
        float rs = rsqrtf(var + BN_EPS);
        float a = rs * g[c];
        a_out[c] = a;
        s_out[c] = b[c] - m * a;
    }
}

// ---------- per-channel partial sums of a bf16 [N,C] buffer (for BN2 stats) ----------
// grid 1024 x 192 threads, 16 rows per block.
__global__ __launch_bounds__(192) void k_stat1b(const short* __restrict__ A,
                                                float* __restrict__ part) {
    const int c = threadIdx.x, b = blockIdx.x;
    const short* p = A + b * 16 * NC + c;
    float s = 0.f, sq = 0.f;
#pragma unroll
    for (int r = 0; r < 16; ++r) {
        float v = bf2f(p[r * NC]);
        s += v; sq = fmaf(v, v, sq);
    }
    part[b * 384 + c] = s;
    part[b * 384 + 192 + c] = sq;
}

// ---------- in-place BN+ReLU on bf16 [N,C] buffer (pre-apply BN1 before kpconv) ----------
// grid 1536 x 256, 8 channels per thread (channel phase repeats every 24 threads).
__global__ __launch_bounds__(256) void k_bnapply(short* __restrict__ T,
                                                 const float* __restrict__ a,
                                                 const float* __restrict__ s) {
    const int t = blockIdx.x * 256 + threadIdx.x;
    const int i = t * 8;
    const int c0 = (t % 24) * 8;
    float4 a0 = *(const float4*)(a + c0), a1 = *(const float4*)(a + c0 + 4);
    float4 s0 = *(const float4*)(s + c0), s1 = *(const float4*)(s + c0 + 4);
    bf16x8 v = *(const bf16x8*)(T + i);
    bf16x8 o;
    o[0] = f2bf(fmaxf(fmaf(a0.x, bf2f(v[0]), s0.x), 0.f));
    o[1] = f2bf(fmaxf(fmaf(a0.y, bf2f(v[1]), s0.y), 0.f));
    o[2] = f2bf(fmaxf(fmaf(a0.z, bf2f(v[2]), s0.z), 0.f));
    o[3] = f2bf(fmaxf(fmaf(a0.w, bf2f(v[3]), s0.w), 0.f));
    o[4] = f2bf(fmaxf(fmaf(a1.x, bf2f(v[4]), s1.x), 0.f));
    o[5] = f2bf(fmaxf(fmaf(a1.y, bf2f(v[5]), s1.y), 0.f));
    o[6] = f2bf(fmaxf(fmaf(a1.z, bf2f(v[6]), s1.z), 0.f));
    o[7] = f2bf(fmaxf(fmaf(a1.w, bf2f(v[7]), s1.w), 0.f));
    *(bf16x8*)(T + i) = o;
}

// ---------- GEMM1: T(bf16) = X(f32) @ W1, + per-block BN partial sums ----------
__global__ __launch_bounds__(256) void k_gemm1(const float* __restrict__ X,
                                               const short* __restrict__ Wb,
                                               short* __restrict__ T,
                                               float* __restrict__ part) {
    __shared__ float red[4][384];
    const int wave = threadIdx.x >> 6, lane = threadIdx.x & 63;
    const int quad = lane >> 4, cl = lane & 15;
    const int r0 = blockIdx.x * 64 + wave * 16;
    const int row = r0 + cl;

    f32x4 acc[12];
#pragma unroll
    for (int nt = 0; nt < 12; ++nt) acc[nt] = (f32x4){0.f, 0.f, 0.f, 0.f};

#pragma unroll
    for (int ks = 0; ks < 6; ++ks) {
        const float* ap = X + row * NC + ks * 32 + quad * 8;
        float4 a0 = *(const float4*)ap;
        float4 a1 = *(const float4*)(ap + 4);
        bf16x8 af;
        af[0] = f2bf(a0.x); af[1] = f2bf(a0.y); af[2] = f2bf(a0.z); af[3] = f2bf(a0.w);
        af[4] = f2bf(a1.x); af[5] = f2bf(a1.y); af[6] = f2bf(a1.z); af[7] = f2bf(a1.w);
#pragma unroll
        for (int nt = 0; nt < 12; ++nt) {
            bf16x8 bf = *(const bf16x8*)(Wb + ((nt * 6 + ks) * 64 + lane) * 8);
            acc[nt] = __builtin_amdgcn_mfma_f32_16x16x32_bf16(af, bf, acc[nt], 0, 0, 0);
        }
    }
#pragma unroll
    for (int nt = 0; nt < 12; ++nt) {
        int c = nt * 16 + cl;
        float s = 0.f, sq = 0.f;
#pragma unroll
        for (int r = 0; r < 4; ++r) {
            float v = acc[nt][r];
            T[(r0 + quad * 4 + r) * NC + c] = f2bf(v);
            s += v; sq = fmaf(v, v, sq);
        }
        s += __shfl_xor(s, 16); s += __shfl_xor(s, 32);
        sq += __shfl_xor(sq, 16); sq += __shfl_xor(sq, 32);
        if (quad == 0) { red[wave][c] = s; red[wave][192 + c] = sq; }
    }
    __syncthreads();
    for (int t = threadIdx.x; t < 384; t += 256)
        part[blockIdx.x * 384 + t] = red[0][t] + red[1][t] + red[2][t] + red[3][t];
}

// ---------- GEMM3: T2(bf16) = relu(bn2(U)) @ W3, + partial sums ----------
__global__ __launch_bounds__(256) void k_gemm3(const short* __restrict__ U,
                                               const float* __restrict__ a2,
                                               const float* __restrict__ s2,
                                               const short* __restrict__ Wb,
                                               short* __restrict__ T2,
                                               float* __restrict__ part) {
    __shared__ float red[4][384];
    const int wave = threadIdx.x >> 6, lane = threadIdx.x & 63;
    const int quad = lane >> 4, cl = lane & 15;
    const int r0 = blockIdx.x * 64 + wave * 16;
    const int row = r0 + cl;

    f32x4 acc[12];
#pragma unroll
    for (int nt = 0; nt < 12; ++nt) acc[nt] = (f32x4){0.f, 0.f, 0.f, 0.f};

#pragma unroll
    for (int ks = 0; ks < 6; ++ks) {
        const int k0 = ks * 32 + quad * 8;
        bf16x8 u8 = *(const bf16x8*)(U + row * NC + k0);
        float4 aa0 = *(const float4*)(a2 + k0), aa1 = *(const float4*)(a2 + k0 + 4);
        float4 ss0 = *(const float4*)(s2 + k0), ss1 = *(const float4*)(s2 + k0 + 4);
        float av[8] = {aa0.x, aa0.y, aa0.z, aa0.w, aa1.x, aa1.y, aa1.z, aa1.w};
        float sv[8] = {ss0.x, ss0.y, ss0.z, ss0.w, ss1.x, ss1.y, ss1.z, ss1.w};
        bf16x8 af;
#pragma unroll
        for (int j = 0; j < 8; ++j)
            af[j] = f2bf(fmaxf(fmaf(av[j], bf2f(u8[j]), sv[j]), 0.f));
#pragma unroll
        for (int nt = 0; nt < 12; ++nt) {
            bf16x8 bf = *(const bf16x8*)(Wb + ((nt * 6 + ks) * 64 + lane) * 8);
            acc[nt] = __builtin_amdgcn_mfma_f32_16x16x32_bf16(af, bf, acc[nt], 0, 0, 0);
        }
    }
#pragma unroll
    for (int nt = 0; nt < 12; ++nt) {
        int c = nt * 16 + cl;
        float s = 0.f, sq = 0.f;
#pragma unroll
        for (int r = 0; r < 4; ++r) {
            float v = acc[nt][r];
            T2[(r0 + quad * 4 + r) * NC + c] = f2bf(v);
            s += v; sq = fmaf(v, v, sq);
        }
        s += __shfl_xor(s, 16); s += __shfl_xor(s, 32);
        sq += __shfl_xor(sq, 16); sq += __shfl_xor(sq, 32);
        if (quad == 0) { red[wave][c] = s; red[wave][192 + c] = sq; }
    }
    __syncthreads();
    for (int t = threadIdx.x; t < 384; t += 256)
        part[blockIdx.x * 384 + t] = red[0][t] + red[1][t] + red[2][t] + red[3][t];
}

// ---------- fused KPConv: U = sum_h (infl @ Wk)[h,c] * Tbn[ref[h], c] ----------
// 256 threads = 4 waves, ONE POINT PER WAVE (grid = N/4). Gather loads hoisted
// ahead of influence+MFMA for latency hiding. Wk frags staged in LDS per block.
// Tbn = relu(bn1(T)) pre-applied by k_bnapply.
__global__ __launch_bounds__(256) void k_kpconv(const float* __restrict__ coord,
                                                const int* __restrict__ ref_idx,
                                                const float* __restrict__ kp,
                                                const short* __restrict__ Wkb,
                                                const short* __restrict__ Tbn,
                                                short* __restrict__ U) {
    __shared__ __align__(16) short wk_s[24 * 64 * 8];   // 24 KiB
    __shared__ float kp_s[64][4];

    const int tid = threadIdx.x;
    // stage Wk fragments (12288 shorts = 1536 float4) + kernel points
    {
        const float4* src = (const float4*)Wkb;
        float4* dst = (float4*)wk_s;
        for (int j = tid; j < 1536; j += 256) dst[j] = src[j];
        if (tid < 64) {
            bool ok = tid < NK;
            kp_s[tid][0] = ok ? kp[tid * 3 + 0] : 0.f;
            kp_s[tid][1] = ok ? kp[tid * 3 + 1] : 0.f;
            kp_s[tid][2] = ok ? kp[tid * 3 + 2] : 0.f;
        }
    }
    __syncthreads();

    const int wave = tid >> 6, lane = tid & 63;
    const int quad = lane >> 4, cl = lane & 15;
    const int n = blockIdx.x * 4 + wave;

    // per-point setup: lanes 0..15 load neighbor idx + relative coords, bcast via shfl
    int idh = 0; float nbx = 0.f, nby = 0.f, nbz = 0.f;
    if (lane < NH) {
        idh = ref_idx[n * NH + lane];
        float cx = coord[n * 3 + 0], cy = coord[n * 3 + 1], cz = coord[n * 3 + 2];
        nbx = coord[idh * 3 + 0] - cx;
        nby = coord[idh * 3 + 1] - cy;
        nbz = coord[idh * 3 + 2] - cz;
    }
    const float nx = __shfl(nbx, cl), ny = __shfl(nby, cl), nz = __shfl(nbz, cl);
    int rowb[4];
#pragma unroll
    for (int r = 0; r < 4; ++r) rowb[r] = __shfl(idh, quad * 4 + r) * NC;

    // ---- hoisted gather: all 48 loads issued before influence+MFMA compute ----
    unsigned short xv[12][4];
    const unsigned short* Tu = (const unsigned short*)Tbn;
#pragma unroll
    for (int nt = 0; nt < 12; ++nt)
#pragma unroll
        for (int r = 0; r < 4; ++r)
            xv[nt][r] = Tu[rowb[r] + nt * 16 + cl];

    // ---- influence A-fragments in registers: A[m = h = cl][k = ks*32+quad*8+j]
    bf16x8 af[2];
#pragma unroll
    for (int ks = 0; ks < 2; ++ks) {
#pragma unroll
        for (int j = 0; j < 8; ++j) {
            int k = ks * 32 + quad * 8 + j;
            float dx = nx - kp_s[k][0];
            float dy = ny - kp_s[k][1];
            float dz = nz - kp_s[k][2];
            float d = sqrtf(fmaf(dx, dx, fmaf(dy, dy, dz * dz)));
            float w = fmaxf(1.f - d, 0.f);         // SIGMA = 1
            if (k >= NK) w = 0.f;
            af[ks][j] = f2bf(w);
        }
    }

    // ---- A = infl @ Wk via MFMA (12 n-tiles x 2 k-steps), B-frags from LDS
    f32x4 acc[12];
#pragma unroll
    for (int nt = 0; nt < 12; ++nt) {
        bf16x8 b0 = *(const bf16x8*)(wk_s + ((nt * 2 + 0) * 64 + lane) * 8);
        bf16x8 b1 = *(const bf16x8*)(wk_s + ((nt * 2 + 1) * 64 + lane) * 8);
        f32x4 z = (f32x4){0.f, 0.f, 0.f, 0.f};
        z = __builtin_amdgcn_mfma_f32_16x16x32_bf16(af[0], b0, z, 0, 0, 0);
        acc[nt] = __builtin_amdgcn_mfma_f32_16x16x32_bf16(af[1], b1, z, 0, 0, 0);
    }

    // ---- aggregate: U[n,c] = sum_h acc[h,c] * xv[h,c]
#pragma unroll
    for (int nt = 0; nt < 12; ++nt) {
        float u = 0.f;
#pragma unroll
        for (int r = 0; r < 4; ++r)
            u = fmaf(acc[nt][r], bf2f((short)xv[nt][r]), u);
        u += __shfl_xor(u, 16);
        u += __shfl_xor(u, 32);
        if (quad == 0) U[n * NC + nt * 16 + cl] = f2bf(u);
    }
}

// ---------- skip: X = relu(X + bn3(T2)); last layer writes d_out instead ----------
__global__ __launch_bounds__(192) void k_bnskip(const short* __restrict__ T2,
                                                const float* __restrict__ a3,
                                                const float* __restrict__ s3,
                                                float* __restrict__ X,
                                                float* __restrict__ out) {
    const int c = threadIdx.x;
    const float a = a3[c], s = s3[c];
    const int base = blockIdx.x * 16;
#pragma unroll
    for (int r = 0; r < 16; ++r) {
        int i = (base + r) * NC + c;
        float v = fmaf(a, bf2f(T2[i]), s);
        float x = fmaxf(X[i] + v, 0.f);
        if (out) out[i] = x; else X[i] = x;
    }
}

extern "C" void kernel_launch(void* const* d_in, const int* in_sizes, int n_in,
                              void* d_out, int out_size, void* d_ws, size_t ws_size,
                              hipStream_t stream) {
    const float* coord = (const float*)d_in[0];
    const float* feat  = (const float*)d_in[1];
    const int*   ridx  = (const int*)d_in[2];
    const float* kp    = (const float*)d_in[3];
    const float* W1    = (const float*)d_in[4];
    const float* Wk    = (const float*)d_in[5];
    const float* W3    = (const float*)d_in[6];
    const float* g1    = (const float*)d_in[7];
    const float* b1    = (const float*)d_in[8];
    const float* g2    = (const float*)d_in[9];
    const float* b2    = (const float*)d_in[10];
    const float* g3    = (const float*)d_in[11];
    const float* b3    = (const float*)d_in[12];
    float* out = (float*)d_out;

    // ws: X f32 | T bf16 | U bf16 | T2 bf16 | Wb bf16 | part f32 | stats f32  ~= 33.4 MB
    float* X   = (float*)d_ws;
    short* T   = (short*)(X + N_PTS * NC);
    short* Ub  = T + N_PTS * NC;
    short* T2  = Ub + N_PTS * NC;
    short* Wb  = T2 + N_PTS * NC;
    float* part = (float*)(Wb + 2 * 86016);
    float* stats = part + 1024 * 384;   // 6 sites x (a[192], s[192])

    k_wfrag<<<336, 64, 0, stream>>>(W1, Wk, W3, Wb);
    k_copy<<<2048, 256, 0, stream>>>(feat, X, N_PTS * NC);

    for (int d = 0; d < ND; ++d) {
        const short* W1b = Wb + d * 86016;
        const short* Wkb = W1b + 36864;
        const short* W3b = W1b + 49152;
        float* st1 = stats + (d * 3 + 0) * 384;
        float* st2 = stats + (d * 3 + 1) * 384;
        float* st3 = stats + (d * 3 + 2) * 384;

        k_gemm1<<<256, 256, 0, stream>>>(X, W1b, T, part);
        k_stat2<<<192, 128, 0, stream>>>(part, 256, g1 + d * NC, b1 + d * NC, st1, st1 + 192);
        k_bnapply<<<1536, 256, 0, stream>>>(T, st1, st1 + 192);
        k_kpconv<<<N_PTS / 4, 256, 0, stream>>>(coord, ridx, kp, Wkb, T, Ub);
        k_stat1b<<<1024, 192, 0, stream>>>(Ub, part);
        k_stat2<<<192, 128, 0, stream>>>(part, 1024, g2 + d * NC, b2 + d * NC, st2, st2 + 192);
        k_gemm3<<<256, 256, 0, stream>>>(Ub, st2, st2 + 192, W3b, T2, part);
        k_stat2<<<192, 128, 0, stream>>>(part, 256, g3 + d * NC, b3 + d * NC, st3, st3 + 192);
        k_bnskip<<<1024, 192, 0, stream>>>(T2, st3, st3 + 192, X,
                                           (d == ND - 1) ? out : (float*)nullptr);
    }
}